// Round 2
// 411.790 us; speedup vs baseline: 1.0277x; 1.0277x over previous
//
#include <hip/hip_runtime.h>
#include <hip/hip_bf16.h>
#include <stdint.h>

#define NB 512
#define NL 128
#define ND 512

typedef __bf16 bf16;
typedef __bf16 bf16x8 __attribute__((ext_vector_type(8)));
typedef float  f32x4  __attribute__((ext_vector_type(4)));

// ------- K1: gather embed rows -> bf16 + partial sumsq; y==2: att^T ------
// grid (NB, 3, 8). y<2: block covers 16 rows of (b, side). y==2: blocks with
// chunk = b*8+zc < 1024 transpose+convert att (256 elems each).
__global__ __launch_bounds__(256) void k_gather(const int* __restrict__ ctx1,
                                                const int* __restrict__ ctx2,
                                                const float* __restrict__ table,
                                                bf16* __restrict__ d1,
                                                bf16* __restrict__ d2,
                                                float* __restrict__ ss,
                                                const float* __restrict__ att,
                                                bf16* __restrict__ attT) {
    const int b = blockIdx.x, side = blockIdx.y, zc = blockIdx.z, t = threadIdx.x;
    if (side == 2) {                      // att transpose slice
        int chunk = b * 8 + zc;
        if (chunk < 1024) {
            int i = chunk * 256 + t;      // over 512*512
            int n = i >> 9, k = i & 511;
            attT[i] = (bf16)att[k * 512 + n];
        }
        return;
    }
    const int* __restrict__ ctx = side ? ctx2 : ctx1;
    bf16* __restrict__ dst = side ? d2 : d1;
    const int base = b * NL;
    const int dv = t & 127, lr = t >> 7;
    float acc = 0.f;
    #pragma unroll
    for (int i = 0; i < 8; ++i) {
        int l = zc * 16 + i * 2 + lr;
        int idx = ctx[base + l];
        float4 v = ((const float4*)table)[(size_t)idx * (ND / 4) + dv];
        acc += v.x * v.x + v.y * v.y + v.z * v.z + v.w * v.w;
        union { bf16 h[4]; uint2 u; } pk;
        pk.h[0] = (bf16)v.x; pk.h[1] = (bf16)v.y;
        pk.h[2] = (bf16)v.z; pk.h[3] = (bf16)v.w;
        *((uint2*)(dst + (size_t)(base + l) * ND) + dv) = pk.u;
    }
    for (int o = 32; o; o >>= 1) acc += __shfl_xor(acc, o);
    __shared__ float red[4];
    if ((t & 63) == 0) red[t >> 6] = acc;
    __syncthreads();
    if (t == 0) atomicAdd(&ss[side * NB + b], red[0] + red[1] + red[2] + red[3]);
}

// ---- FUSED: per-batch block (512 thr). Phase1: T = A@attT^T kept in LDS
//      (128KB, swizzled). Phase2: S = tanh(T@Bb^T*sc) + sums/softmax/
//      weighted-sums/logit. Eliminates the 67MB T write + 67MB T read of
//      the old 2-kernel split. Total static LDS = 144 KB (1 block/CU).
__global__ __launch_bounds__(512) void k_fused(
        const bf16* __restrict__ Ab, const bf16* __restrict__ attT,
        const bf16* __restrict__ Bb, float* __restrict__ Sout,
        const float* __restrict__ ss,
        const float* __restrict__ w_pred, const float* __restrict__ b_pred,
        float* __restrict__ logits) {
    const int b = blockIdx.x;
    const int row0 = b * NL;
    const int tid = threadIdx.x;
    const int lane = tid & 63, w = tid >> 6;
    const int lm = lane & 15, quad = lane >> 4;

    // LDS regions (all aliased into one 144 KB arena):
    //   phase1 k-loop : stA [128][64] @0 (16K) | stT [512][64] @16K (64K)
    //   phase1 epilog : Tls [8][128][64] @0 (128K)
    //   phase2 k-loop : Tls @0 (128K) | Bst [128][64] @128K (16K)
    //   S epilogue    : rowb/colb/wrow/wcol @128K (Bst dead)
    //   final         : pA [8][512] @0 | pB [8][512] @16K (Tls dead)
    __shared__ __align__(16) char smem[147456];
    bf16* Tls = (bf16*)smem;                 // [8 ks][128 m][64], swizzled
    bf16* stA = (bf16*)smem;                 // phase1: [128][64]  (16 KB)
    bf16* stT = (bf16*)(smem + 16384);       // phase1: [512][64]  (64 KB)
    bf16* Bst = (bf16*)(smem + 131072);      // phase2: [128][64]  (16 KB)
    float* pA = (float*)smem;                // final: [8][512]
    float* pB = (float*)(smem + 16384);      // final: [8][512]
    float* rowb = (float*)(smem + 131072);             // [4][128]
    float* colb = (float*)(smem + 131072 + 2048);      // [2][128]
    float* wrow = (float*)(smem + 131072 + 3072);      // [128]
    float* wcol = (float*)(smem + 131072 + 3584);      // [128]

    // ---------------- Phase 1: T = A @ attT^T ----------------
    const int wm1 = (w & 1) * 64;            // 2 m-halves
    const int wn1 = (w >> 1) * 128;          // 4 n-chunks
    f32x4 acc1[4][8] = {};

    for (int k0 = 0; k0 < ND; k0 += 64) {
        #pragma unroll
        for (int i = 0; i < 2; ++i) {        // A-tile: 128 rows x 64 k
            int s = i * 512 + tid;
            int r = s >> 3, c = (s & 7) ^ (r & 7);
            __builtin_amdgcn_global_load_lds(
                (const __attribute__((address_space(1))) void*)(Ab + (size_t)(row0 + r) * ND + k0 + c * 8),
                (__attribute__((address_space(3))) void*)(stA + (size_t)(i * 512 + w * 64) * 8),
                16, 0, 0);
        }
        #pragma unroll
        for (int i = 0; i < 8; ++i) {        // attT-tile: 512 rows x 64 k (L2)
            int s = i * 512 + tid;
            int r = s >> 3, c = (s & 7) ^ (r & 7);
            __builtin_amdgcn_global_load_lds(
                (const __attribute__((address_space(1))) void*)(attT + (size_t)r * ND + k0 + c * 8),
                (__attribute__((address_space(3))) void*)(stT + (size_t)(i * 512 + w * 64) * 8),
                16, 0, 0);
        }
        __syncthreads();
        #pragma unroll
        for (int kk = 0; kk < 2; ++kk) {
            bf16x8 af[4], bfm[8];
            const int ca = (kk * 4 + quad) ^ (lm & 7);
            #pragma unroll
            for (int t4 = 0; t4 < 4; ++t4)
                af[t4] = *(const bf16x8*)&stA[(wm1 + t4 * 16 + lm) * 64 + ca * 8];
            #pragma unroll
            for (int t8 = 0; t8 < 8; ++t8)
                bfm[t8] = *(const bf16x8*)&stT[(wn1 + t8 * 16 + lm) * 64 + ca * 8];
            #pragma unroll
            for (int im = 0; im < 4; ++im)
                #pragma unroll
                for (int jn = 0; jn < 8; ++jn)
                    acc1[im][jn] = __builtin_amdgcn_mfma_f32_16x16x32_bf16(
                        af[im], bfm[jn], acc1[im][jn], 0, 0, 0);
        }
        __syncthreads();
    }

    // Phase-1 epilogue: acc1 -> bf16 into swizzled Tls (stage region dead).
    // Layout matches phase-2 reader: Tls[ks][r][slot][e] = T[r][ks*64+(slot^(r&7))*8+e]
    #pragma unroll
    for (int im = 0; im < 4; ++im)
    #pragma unroll
    for (int jn = 0; jn < 8; ++jn)
    #pragma unroll
    for (int p = 0; p < 4; ++p) {
        int m = wm1 + im * 16 + quad * 4 + p;   // C/D: col=lane&15, row=quad*4+reg
        int n = wn1 + jn * 16 + lm;
        int ks = n >> 6, c = n & 63;
        int pos = (((c >> 3) ^ (m & 7)) << 3) + (c & 7);
        Tls[ks * 8192 + m * 64 + pos] = (bf16)acc1[im][jn][p];
    }
    __syncthreads();

    // ---------------- Phase 2: S = T @ Bb^T ----------------
    const int wm2 = (w & 1) * 64;            // 2 m-halves
    const int wn2 = (w >> 1) * 32;           // 4 n-chunks of 32
    f32x4 acc2[4][2] = {};

    for (int k0 = 0; k0 < ND; k0 += 64) {
        #pragma unroll
        for (int i = 0; i < 2; ++i) {        // B-tile: 128 rows x 64 k
            int s = i * 512 + tid;
            int r = s >> 3, c = (s & 7) ^ (r & 7);
            __builtin_amdgcn_global_load_lds(
                (const __attribute__((address_space(1))) void*)(Bb + (size_t)(row0 + r) * ND + k0 + c * 8),
                (__attribute__((address_space(3))) void*)(Bst + (size_t)(i * 512 + w * 64) * 8),
                16, 0, 0);
        }
        __syncthreads();
        const bf16* Tk = Tls + (k0 >> 6) * 8192;
        #pragma unroll
        for (int kk = 0; kk < 2; ++kk) {
            bf16x8 af[4], bf2[2];
            const int ca = (kk * 4 + quad) ^ (lm & 7);
            #pragma unroll
            for (int t4 = 0; t4 < 4; ++t4)
                af[t4] = *(const bf16x8*)&Tk[(wm2 + t4 * 16 + lm) * 64 + ca * 8];
            #pragma unroll
            for (int t2 = 0; t2 < 2; ++t2)
                bf2[t2] = *(const bf16x8*)&Bst[(wn2 + t2 * 16 + lm) * 64 + ca * 8];
            #pragma unroll
            for (int im = 0; im < 4; ++im)
                #pragma unroll
                for (int jn = 0; jn < 2; ++jn)
                    acc2[im][jn] = __builtin_amdgcn_mfma_f32_16x16x32_bf16(
                        af[im], bf2[jn], acc2[im][jn], 0, 0, 0);
        }
        __syncthreads();
    }

    // ---- epilogue: tanh + S store + row/col sums ----
    const float sc = rsqrtf(ss[b] * ss[NB + b]);   // 1/(na*nb), deferred norm
    float* __restrict__ Sb = Sout + (size_t)b * NL * NL;
    #pragma unroll
    for (int im = 0; im < 4; ++im)
    #pragma unroll
    for (int jn = 0; jn < 2; ++jn)
    #pragma unroll
    for (int p = 0; p < 4; ++p) {
        float v = tanhf(acc2[im][jn][p] * sc);
        acc2[im][jn][p] = v;
        int m = wm2 + im * 16 + quad * 4 + p;
        int n = wn2 + jn * 16 + lm;
        __builtin_nontemporal_store(v, &Sb[m * NL + n]);
    }
    #pragma unroll
    for (int im = 0; im < 4; ++im)
    #pragma unroll
    for (int p = 0; p < 4; ++p) {
        float r = acc2[im][0][p] + acc2[im][1][p];   // 32 cols of this wave
        r += __shfl_xor(r, 1); r += __shfl_xor(r, 2);
        r += __shfl_xor(r, 4); r += __shfl_xor(r, 8);
        if (lm == 0) rowb[(w >> 1) * NL + wm2 + im * 16 + quad * 4 + p] = r;
    }
    #pragma unroll
    for (int jn = 0; jn < 2; ++jn) {
        float cv = 0.f;
        #pragma unroll
        for (int im = 0; im < 4; ++im)
            #pragma unroll
            for (int p = 0; p < 4; ++p) cv += acc2[im][jn][p];
        cv += __shfl_xor(cv, 16); cv += __shfl_xor(cv, 32);
        if (quad == 0) colb[(w & 1) * NL + wn2 + jn * 16 + lm] = cv;
    }
    __syncthreads();

    // ---- softmax over means (wave0: rows, wave1: cols) ----
    if (tid < 64) {
        float a  = (rowb[0 * NL + tid] + rowb[1 * NL + tid] + rowb[2 * NL + tid] + rowb[3 * NL + tid]) * (1.f / NL);
        float c2 = (rowb[0 * NL + tid + 64] + rowb[1 * NL + tid + 64] + rowb[2 * NL + tid + 64] + rowb[3 * NL + tid + 64]) * (1.f / NL);
        float mx = fmaxf(a, c2);
        for (int o = 32; o; o >>= 1) mx = fmaxf(mx, __shfl_xor(mx, o));
        float e0 = expf(a - mx), e1 = expf(c2 - mx);
        float s = e0 + e1;
        for (int o = 32; o; o >>= 1) s += __shfl_xor(s, o);
        float inv = 1.f / s;
        wrow[tid] = e0 * inv; wrow[tid + 64] = e1 * inv;
    } else if (tid < 128) {
        int q = tid - 64;
        float a  = (colb[0 * NL + q] + colb[1 * NL + q]) * (1.f / NL);
        float c2 = (colb[0 * NL + q + 64] + colb[1 * NL + q + 64]) * (1.f / NL);
        float mx = fmaxf(a, c2);
        for (int o = 32; o; o >>= 1) mx = fmaxf(mx, __shfl_xor(mx, o));
        float e0 = expf(a - mx), e1 = expf(c2 - mx);
        float s = e0 + e1;
        for (int o = 32; o; o >>= 1) s += __shfl_xor(s, o);
        float inv = 1.f / s;
        wcol[q] = e0 * inv; wcol[q + 64] = e1 * inv;
    }
    __syncthreads();

    // ---- weighted sums of A/B rows (Tls region dead -> pA/pB) ----
    const int c = tid & 63, g = tid >> 6;
    const bf16* __restrict__ Abase = Ab + (size_t)b * NL * ND;
    const bf16* __restrict__ Bbase = Bb + (size_t)b * NL * ND;
    float aacc[8] = {}, bacc[8] = {};
    for (int l = g; l < NL; l += 8) {
        float wr = wrow[l], wc = wcol[l];
        bf16x8 va = *(const bf16x8*)(Abase + (size_t)l * ND + c * 8);
        bf16x8 vb = *(const bf16x8*)(Bbase + (size_t)l * ND + c * 8);
        #pragma unroll
        for (int j = 0; j < 8; ++j) {
            aacc[j] += wr * (float)va[j];
            bacc[j] += wc * (float)vb[j];
        }
    }
    #pragma unroll
    for (int j = 0; j < 8; ++j) {
        pA[g * ND + c * 8 + j] = aacc[j];
        pB[g * ND + c * 8 + j] = bacc[j];
    }
    __syncthreads();

    if (tid < 64) {
        float dot = 0.f;
        #pragma unroll
        for (int j = 0; j < 8; ++j) {
            int d = tid * 8 + j;
            float na = 0.f, nb = 0.f;
            #pragma unroll
            for (int g2 = 0; g2 < 8; ++g2) {
                na += pA[g2 * ND + d];
                nb += pB[g2 * ND + d];
            }
            dot += na * nb * w_pred[d];
        }
        for (int o = 32; o; o >>= 1) dot += __shfl_xor(dot, o);
        if (tid == 0)
            logits[b] = dot * rsqrtf(ss[b]) * rsqrtf(ss[NB + b]) + b_pred[0];
    }
}

extern "C" void kernel_launch(void* const* d_in, const int* in_sizes, int n_in,
                              void* d_out, int out_size, void* d_ws, size_t ws_size,
                              hipStream_t stream) {
    const int*   t1c = (const int*)d_in[2];
    const int*   t2c = (const int*)d_in[3];
    const float* emb = (const float*)d_in[4];
    const float* att = (const float*)d_in[5];
    const float* wp  = (const float*)d_in[6];
    const float* bp  = (const float*)d_in[7];

    float* out    = (float*)d_out;
    float* logits = out;
    float* S      = out + NB;      // outputs: logits(512) then S(512*128*128)

    char* ws = (char*)d_ws;
    bf16*  Ab   = (bf16*)(ws);                              // 67,108,864 B
    bf16*  Bb   = (bf16*)(ws + 67108864);                   // 67,108,864 B
    bf16*  attT = (bf16*)(ws + 134217728);                  //    524,288 B
    float* ss   = (float*)(ws + 134742016);                 //      4,096 B

    hipMemsetAsync(ss, 0, 4096, stream);
    // gather (y=0,1) + att transpose (y=2) in one launch
    k_gather<<<dim3(NB, 3, 8), 256, 0, stream>>>(t1c, t2c, emb, Ab, Bb, ss, att, attT);
    // fused: T in LDS, S + softmax + weighted sums + logits
    k_fused<<<dim3(NB), 512, 0, stream>>>(Ab, attT, Bb, S, ss, wp, bp, logits);
}

// Round 3
// 406.790 us; speedup vs baseline: 1.0403x; 1.0123x over previous
//
#include <hip/hip_runtime.h>
#include <hip/hip_bf16.h>
#include <stdint.h>

#define NB 512
#define NL 128
#define ND 512

typedef __bf16 bf16;
typedef __bf16 bf16x8 __attribute__((ext_vector_type(8)));
typedef float  f32x4  __attribute__((ext_vector_type(4)));

#define GLDS(src, dst) __builtin_amdgcn_global_load_lds( \
    (const __attribute__((address_space(1))) void*)(src), \
    (__attribute__((address_space(3))) void*)(dst), 16, 0, 0)

// ------- K1: gather embed rows -> bf16 + partial sumsq; y==2: att^T ------
__global__ __launch_bounds__(256) void k_gather(const int* __restrict__ ctx1,
                                                const int* __restrict__ ctx2,
                                                const float* __restrict__ table,
                                                bf16* __restrict__ d1,
                                                bf16* __restrict__ d2,
                                                float* __restrict__ ss,
                                                const float* __restrict__ att,
                                                bf16* __restrict__ attT) {
    const int b = blockIdx.x, side = blockIdx.y, zc = blockIdx.z, t = threadIdx.x;
    if (side == 2) {                      // att transpose slice
        int chunk = b * 8 + zc;
        if (chunk < 1024) {
            int i = chunk * 256 + t;      // over 512*512
            int n = i >> 9, k = i & 511;
            attT[i] = (bf16)att[k * 512 + n];
        }
        return;
    }
    const int* __restrict__ ctx = side ? ctx2 : ctx1;
    bf16* __restrict__ dst = side ? d2 : d1;
    const int base = b * NL;
    const int dv = t & 127, lr = t >> 7;
    int idxs[8];
    #pragma unroll
    for (int i = 0; i < 8; ++i) idxs[i] = ctx[base + zc * 16 + i * 2 + lr];
    float acc = 0.f;
    #pragma unroll
    for (int i = 0; i < 8; ++i) {
        int l = zc * 16 + i * 2 + lr;
        float4 v = ((const float4*)table)[(size_t)idxs[i] * (ND / 4) + dv];
        acc += v.x * v.x + v.y * v.y + v.z * v.z + v.w * v.w;
        union { bf16 h[4]; uint2 u; } pk;
        pk.h[0] = (bf16)v.x; pk.h[1] = (bf16)v.y;
        pk.h[2] = (bf16)v.z; pk.h[3] = (bf16)v.w;
        *((uint2*)(dst + (size_t)(base + l) * ND) + dv) = pk.u;
    }
    for (int o = 32; o; o >>= 1) acc += __shfl_xor(acc, o);
    __shared__ float red[4];
    if ((t & 63) == 0) red[t >> 6] = acc;
    __syncthreads();
    if (t == 0) atomicAdd(&ss[side * NB + b], red[0] + red[1] + red[2] + red[3]);
}

// ---- FUSED: per-batch block (512 thr). Phase1: T = A@attT^T kept in LDS.
//      BK=32 double-buffered stages (T3 minimal 2-phase: issue next stage
//      BEFORE current ds_read+MFMA so loads hide under compute; the
//      implicit vmcnt(0)+barrier at iteration end then waits only residue).
//      BK=32 => 64-B row stride => wave read pattern {row=lm, chunk=quad}
//      covers 64 consecutive 16B slots: bank-conflict-free, NO swizzle.
//      LDS arena 148 KB: phase1 stages 2x40K @0..80K (time-aliased with
//      T[16][128][32] 128K @0); sB dbuf 2x8K @128K; smalls @144K.
__global__ __launch_bounds__(512) void k_fused(
        const bf16* __restrict__ Ab, const bf16* __restrict__ attT,
        const bf16* __restrict__ Bb, float* __restrict__ Sout,
        const float* __restrict__ ss,
        const float* __restrict__ w_pred, const float* __restrict__ b_pred,
        float* __restrict__ logits) {
    const int b = blockIdx.x;
    const int row0 = b * NL;
    const int tid = threadIdx.x;
    const int lane = tid & 63, w = tid >> 6;
    const int lm = lane & 15, quad = lane >> 4;

    __shared__ __align__(16) char smem[151552];
    bf16* sA0 = (bf16*)smem;                  // [128][32] 8K
    bf16* sT0 = (bf16*)(smem + 8192);         // [512][32] 32K
    bf16* sA1 = (bf16*)(smem + 40960);
    bf16* sT1 = (bf16*)(smem + 49152);
    bf16* Tls = (bf16*)smem;                  // [16ks][128m][32] 128K, after loop
    bf16* sB0 = (bf16*)(smem + 131072);       // [128][32] 8K
    bf16* sB1 = (bf16*)(smem + 139264);       // 8K
    float* pA = (float*)smem;                 // final: [8][512]
    float* pB = (float*)(smem + 16384);       // final: [8][512]
    float* rowb = (float*)(smem + 147456);            // [4][128]
    float* colb = (float*)(smem + 147456 + 2048);     // [2][128]
    float* wrow = (float*)(smem + 147456 + 3072);     // [128]
    float* wcol = (float*)(smem + 147456 + 3584);     // [128]

    // ---------------- Phase 1: T = A @ attT^T ----------------
    const int wm1 = (w & 1) * 64;             // 2 m-halves
    const int wn1 = (w >> 1) * 128;           // 4 n-chunks
    f32x4 acc1[4][8] = {};

    const int rA = tid >> 2, cA = tid & 3;    // stage decomposition

    // prologue: stage k-step 0 into buf0
    GLDS(Ab + (size_t)(row0 + rA) * ND + 0 + cA * 8, sA0 + tid * 8);
    #pragma unroll
    for (int i = 0; i < 4; ++i) {
        int s = i * 512 + tid, r = s >> 2, c = s & 3;
        GLDS(attT + (size_t)r * ND + 0 + c * 8, sT0 + s * 8);
    }
    __syncthreads();

    for (int t = 0; t < 16; ++t) {
        if (t < 15) {                         // prefetch next k-step
            const int k0 = (t + 1) * 32;
            bf16* dA = (t & 1) ? sA0 : sA1;
            bf16* dT = (t & 1) ? sT0 : sT1;
            GLDS(Ab + (size_t)(row0 + rA) * ND + k0 + cA * 8, dA + tid * 8);
            #pragma unroll
            for (int i = 0; i < 4; ++i) {
                int s = i * 512 + tid, r = s >> 2, c = s & 3;
                GLDS(attT + (size_t)r * ND + k0 + c * 8, dT + s * 8);
            }
        } else {                              // prefetch phase-2's first B-tile
            GLDS(Bb + (size_t)(row0 + rA) * ND + 0 + cA * 8, sB0 + tid * 8);
        }
        const bf16* A_ = (t & 1) ? sA1 : sA0;
        const bf16* T_ = (t & 1) ? sT1 : sT0;
        bf16x8 af[4], bfm[8];
        #pragma unroll
        for (int t4 = 0; t4 < 4; ++t4)
            af[t4] = *(const bf16x8*)&A_[(wm1 + t4 * 16 + lm) * 32 + quad * 8];
        #pragma unroll
        for (int t8 = 0; t8 < 8; ++t8)
            bfm[t8] = *(const bf16x8*)&T_[(wn1 + t8 * 16 + lm) * 32 + quad * 8];
        #pragma unroll
        for (int im = 0; im < 4; ++im)
            #pragma unroll
            for (int jn = 0; jn < 8; ++jn)
                acc1[im][jn] = __builtin_amdgcn_mfma_f32_16x16x32_bf16(
                    af[im], bfm[jn], acc1[im][jn], 0, 0, 0);
        __syncthreads();
    }

    // Phase-1 epilogue: acc1 -> bf16 into swizzled Tls (stage bufs dead).
    // Tls[ks][m][pos][e] with pos = kq ^ ((m>>2)&3), kq=(n>>3)&3, e=n&7.
    #pragma unroll
    for (int im = 0; im < 4; ++im)
    #pragma unroll
    for (int jn = 0; jn < 8; ++jn)
    #pragma unroll
    for (int p = 0; p < 4; ++p) {
        int m = wm1 + im * 16 + quad * 4 + p;   // C/D: col=lane&15, row=quad*4+reg
        int n = wn1 + jn * 16 + lm;
        int ks = n >> 5, kq = (n >> 3) & 3, e = n & 7;
        int pos = kq ^ ((m >> 2) & 3);
        Tls[ks * 4096 + m * 32 + pos * 8 + e] = (bf16)acc1[im][jn][p];
    }
    __syncthreads();

    // ---------------- Phase 2: S = T @ Bb^T ----------------
    const int wm2 = (w & 1) * 64;             // 2 m-halves
    const int wn2 = (w >> 1) * 32;            // 4 n-chunks of 32
    f32x4 acc2[4][2] = {};

    for (int t = 0; t < 16; ++t) {
        if (t < 15) {                         // prefetch next B-tile
            bf16* dB = (t & 1) ? sB0 : sB1;
            GLDS(Bb + (size_t)(row0 + rA) * ND + (t + 1) * 32 + cA * 8, dB + tid * 8);
        }
        const bf16* B_ = (t & 1) ? sB1 : sB0;
        bf16x8 af[4], bf2[2];
        #pragma unroll
        for (int t4 = 0; t4 < 4; ++t4) {
            int r = wm2 + t4 * 16 + lm;
            af[t4] = *(const bf16x8*)&Tls[t * 4096 + r * 32 + ((quad ^ ((r >> 2) & 3))) * 8];
        }
        #pragma unroll
        for (int t2 = 0; t2 < 2; ++t2)
            bf2[t2] = *(const bf16x8*)&B_[(wn2 + t2 * 16 + lm) * 32 + quad * 8];
        #pragma unroll
        for (int im = 0; im < 4; ++im)
            #pragma unroll
            for (int jn = 0; jn < 2; ++jn)
                acc2[im][jn] = __builtin_amdgcn_mfma_f32_16x16x32_bf16(
                    af[im], bf2[jn], acc2[im][jn], 0, 0, 0);
        __syncthreads();
    }

    // ---- epilogue: tanh + S store + row/col sums ----
    const float sc = rsqrtf(ss[b] * ss[NB + b]);   // 1/(na*nb), deferred norm
    float* __restrict__ Sb = Sout + (size_t)b * NL * NL;
    #pragma unroll
    for (int im = 0; im < 4; ++im)
    #pragma unroll
    for (int jn = 0; jn < 2; ++jn)
    #pragma unroll
    for (int p = 0; p < 4; ++p) {
        float v = tanhf(acc2[im][jn][p] * sc);
        acc2[im][jn][p] = v;
        int m = wm2 + im * 16 + quad * 4 + p;
        int n = wn2 + jn * 16 + lm;
        __builtin_nontemporal_store(v, &Sb[m * NL + n]);
    }
    #pragma unroll
    for (int im = 0; im < 4; ++im)
    #pragma unroll
    for (int p = 0; p < 4; ++p) {
        float r = acc2[im][0][p] + acc2[im][1][p];   // 32 cols of this wave
        r += __shfl_xor(r, 1); r += __shfl_xor(r, 2);
        r += __shfl_xor(r, 4); r += __shfl_xor(r, 8);
        if (lm == 0) rowb[(w >> 1) * NL + wm2 + im * 16 + quad * 4 + p] = r;
    }
    #pragma unroll
    for (int jn = 0; jn < 2; ++jn) {
        float cv = 0.f;
        #pragma unroll
        for (int im = 0; im < 4; ++im)
            #pragma unroll
            for (int p = 0; p < 4; ++p) cv += acc2[im][jn][p];
        cv += __shfl_xor(cv, 16); cv += __shfl_xor(cv, 32);
        if (quad == 0) colb[(w & 1) * NL + wn2 + jn * 16 + lm] = cv;
    }
    __syncthreads();

    // ---- softmax over means (wave0: rows, wave1: cols) ----
    if (tid < 64) {
        float a  = (rowb[0 * NL + tid] + rowb[1 * NL + tid] + rowb[2 * NL + tid] + rowb[3 * NL + tid]) * (1.f / NL);
        float c2 = (rowb[0 * NL + tid + 64] + rowb[1 * NL + tid + 64] + rowb[2 * NL + tid + 64] + rowb[3 * NL + tid + 64]) * (1.f / NL);
        float mx = fmaxf(a, c2);
        for (int o = 32; o; o >>= 1) mx = fmaxf(mx, __shfl_xor(mx, o));
        float e0 = expf(a - mx), e1 = expf(c2 - mx);
        float s = e0 + e1;
        for (int o = 32; o; o >>= 1) s += __shfl_xor(s, o);
        float inv = 1.f / s;
        wrow[tid] = e0 * inv; wrow[tid + 64] = e1 * inv;
    } else if (tid < 128) {
        int q = tid - 64;
        float a  = (colb[0 * NL + q] + colb[1 * NL + q]) * (1.f / NL);
        float c2 = (colb[0 * NL + q + 64] + colb[1 * NL + q + 64]) * (1.f / NL);
        float mx = fmaxf(a, c2);
        for (int o = 32; o; o >>= 1) mx = fmaxf(mx, __shfl_xor(mx, o));
        float e0 = expf(a - mx), e1 = expf(c2 - mx);
        float s = e0 + e1;
        for (int o = 32; o; o >>= 1) s += __shfl_xor(s, o);
        float inv = 1.f / s;
        wcol[q] = e0 * inv; wcol[q + 64] = e1 * inv;
    }
    __syncthreads();

    // ---- weighted sums of A/B rows (Tls region dead -> pA/pB) ----
    const int c = tid & 63, g = tid >> 6;
    const bf16* __restrict__ Abase = Ab + (size_t)b * NL * ND;
    const bf16* __restrict__ Bbase = Bb + (size_t)b * NL * ND;
    float aacc[8] = {}, bacc[8] = {};
    for (int l = g; l < NL; l += 8) {
        float wr = wrow[l], wc = wcol[l];
        bf16x8 va = *(const bf16x8*)(Abase + (size_t)l * ND + c * 8);
        bf16x8 vb = *(const bf16x8*)(Bbase + (size_t)l * ND + c * 8);
        #pragma unroll
        for (int j = 0; j < 8; ++j) {
            aacc[j] += wr * (float)va[j];
            bacc[j] += wc * (float)vb[j];
        }
    }
    #pragma unroll
    for (int j = 0; j < 8; ++j) {
        pA[g * ND + c * 8 + j] = aacc[j];
        pB[g * ND + c * 8 + j] = bacc[j];
    }
    __syncthreads();

    if (tid < 64) {
        float dot = 0.f;
        #pragma unroll
        for (int j = 0; j < 8; ++j) {
            int d = tid * 8 + j;
            float na = 0.f, nb = 0.f;
            #pragma unroll
            for (int g2 = 0; g2 < 8; ++g2) {
                na += pA[g2 * ND + d];
                nb += pB[g2 * ND + d];
            }
            dot += na * nb * w_pred[d];
        }
        for (int o = 32; o; o >>= 1) dot += __shfl_xor(dot, o);
        if (tid == 0)
            logits[b] = dot * rsqrtf(ss[b]) * rsqrtf(ss[NB + b]) + b_pred[0];
    }
}

extern "C" void kernel_launch(void* const* d_in, const int* in_sizes, int n_in,
                              void* d_out, int out_size, void* d_ws, size_t ws_size,
                              hipStream_t stream) {
    const int*   t1c = (const int*)d_in[2];
    const int*   t2c = (const int*)d_in[3];
    const float* emb = (const float*)d_in[4];
    const float* att = (const float*)d_in[5];
    const float* wp  = (const float*)d_in[6];
    const float* bp  = (const float*)d_in[7];

    float* out    = (float*)d_out;
    float* logits = out;
    float* S      = out + NB;      // outputs: logits(512) then S(512*128*128)

    char* ws = (char*)d_ws;
    bf16*  Ab   = (bf16*)(ws);                              // 67,108,864 B
    bf16*  Bb   = (bf16*)(ws + 67108864);                   // 67,108,864 B
    bf16*  attT = (bf16*)(ws + 134217728);                  //    524,288 B
    float* ss   = (float*)(ws + 134742016);                 //      4,096 B

    hipMemsetAsync(ss, 0, 4096, stream);
    // gather (y=0,1) + att transpose (y=2) in one launch
    k_gather<<<dim3(NB, 3, 8), 256, 0, stream>>>(t1c, t2c, emb, Ab, Bb, ss, att, attT);
    // fused: T in LDS (pipelined BK=32 dbuf), S + softmax + sums + logits
    k_fused<<<dim3(NB), 512, 0, stream>>>(Ab, attT, Bb, S, ss, wp, bp, logits);
}

// Round 4
// 387.781 us; speedup vs baseline: 1.0913x; 1.0490x over previous
//
#include <hip/hip_runtime.h>
#include <hip/hip_bf16.h>
#include <stdint.h>

#define NB 512
#define NL 128
#define ND 512

typedef __bf16 bf16;
typedef __bf16 bf16x8 __attribute__((ext_vector_type(8)));
typedef float  f32x4  __attribute__((ext_vector_type(4)));

#define GLDS(src, dst) __builtin_amdgcn_global_load_lds( \
    (const __attribute__((address_space(1))) void*)(src), \
    (__attribute__((address_space(3))) void*)(dst), 16, 0, 0)

// ------- K0: att^T -> bf16 (512KB, shared by all mega blocks) -------
__global__ __launch_bounds__(256) void k_attT(const float* __restrict__ att,
                                              bf16* __restrict__ attT) {
    int i = blockIdx.x * 256 + threadIdx.x;   // over 512*512
    int n = i >> 9, k = i & 511;
    attT[i] = (bf16)att[k * 512 + n];
}

// ---- MEGA: per-batch block (512 thr).
//  pre : gather 256 random table rows f32 -> bf16 Ab/Bb (global, L2-hot)
//        + block-local sumsq (no atomics, no memset).
//  ph1 : T = A @ attT^T, BK=32 dbuf prefetch, T -> 128KB swizzled LDS.
//  ph2 : S = tanh(T@B^T*sc)  AND  G = A@diag(w_pred)@B^T (2nd accumulator,
//        w applied to B-fragment in VALU). Eliminates the 134MB epilogue
//        re-read of Ab/Bb: logit = sc * wrow^T G wcol.
//  LDS 160KB exact: T 128K + sB dbuf 16K + sA2 dbuf 16K; smalls time-aliased.
__global__ __launch_bounds__(512) void k_mega(
        const int* __restrict__ ctx1, const int* __restrict__ ctx2,
        const float* __restrict__ table, const bf16* __restrict__ attT,
        bf16* __restrict__ Ab, bf16* __restrict__ Bb,
        float* __restrict__ Sout, const float* __restrict__ w_pred,
        const float* __restrict__ b_pred, float* __restrict__ logits) {
    const int b = blockIdx.x, row0 = b * NL, tid = threadIdx.x;
    const int lane = tid & 63, w = tid >> 6;
    const int lm = lane & 15, quad = lane >> 4;

    __shared__ __align__(16) char smem[163840];
    bf16* sA0 = (bf16*)smem;                  // ph1 A stage [128][32] 8K
    bf16* sA1 = (bf16*)(smem + 8192);
    bf16* sT0 = (bf16*)(smem + 16384);        // ph1 attT stage [512][32] 32K
    bf16* sT1 = (bf16*)(smem + 49152);
    bf16* Tls = (bf16*)smem;                  // [16ks][128m][32] 128K (post-ph1)
    bf16* sB0 = (bf16*)(smem + 131072);       // ph2 B stage 8K dbuf
    bf16* sB1 = (bf16*)(smem + 139264);
    bf16* sC0 = (bf16*)(smem + 147456);       // ph2 A stage 8K dbuf
    bf16* sC1 = (bf16*)(smem + 155648);
    float* red  = (float*)(smem + 1024);      // pre-phase [16]
    float* rowb = (float*)smem;               // post-ph2 [4][128]
    float* colb = (float*)(smem + 2048);      // [2][128]
    float* wrow = (float*)(smem + 3072);      // [128]
    float* wcol = (float*)(smem + 3584);      // [128]
    float* red2 = (float*)(smem + 2048);      // final wave partials [8]

    // ---------------- pre-phase: gather + convert + sumsq ----------------
    const int r8 = tid >> 6, c8 = tid & 63;   // 8 rows/pass, 64 lanes/row
    float pa = 0.f, pb = 0.f;
    #pragma unroll 4
    for (int j = 0; j < 16; ++j) {
        int l = j * 8 + r8;
        int ia = ctx1[row0 + l], ib = ctx2[row0 + l];
        const float4* ra = (const float4*)table + (size_t)ia * (ND / 4) + c8 * 2;
        const float4* rb = (const float4*)table + (size_t)ib * (ND / 4) + c8 * 2;
        float4 a0 = ra[0], a1 = ra[1];
        float4 b0 = rb[0], b1 = rb[1];
        pa += a0.x*a0.x + a0.y*a0.y + a0.z*a0.z + a0.w*a0.w
            + a1.x*a1.x + a1.y*a1.y + a1.z*a1.z + a1.w*a1.w;
        pb += b0.x*b0.x + b0.y*b0.y + b0.z*b0.z + b0.w*b0.w
            + b1.x*b1.x + b1.y*b1.y + b1.z*b1.z + b1.w*b1.w;
        union { bf16 h[8]; uint4 u; } ua, ub;
        ua.h[0]=(bf16)a0.x; ua.h[1]=(bf16)a0.y; ua.h[2]=(bf16)a0.z; ua.h[3]=(bf16)a0.w;
        ua.h[4]=(bf16)a1.x; ua.h[5]=(bf16)a1.y; ua.h[6]=(bf16)a1.z; ua.h[7]=(bf16)a1.w;
        ub.h[0]=(bf16)b0.x; ub.h[1]=(bf16)b0.y; ub.h[2]=(bf16)b0.z; ub.h[3]=(bf16)b0.w;
        ub.h[4]=(bf16)b1.x; ub.h[5]=(bf16)b1.y; ub.h[6]=(bf16)b1.z; ub.h[7]=(bf16)b1.w;
        *(uint4*)(Ab + (size_t)(row0 + l) * ND + c8 * 8) = ua.u;
        *(uint4*)(Bb + (size_t)(row0 + l) * ND + c8 * 8) = ub.u;
    }
    for (int o = 32; o; o >>= 1) { pa += __shfl_xor(pa, o); pb += __shfl_xor(pb, o); }
    if (lane == 0) { red[w * 2] = pa; red[w * 2 + 1] = pb; }
    __syncthreads();                          // also drains Ab/Bb stores
    float ssA = 0.f, ssB = 0.f;
    #pragma unroll
    for (int i = 0; i < 8; ++i) { ssA += red[i * 2]; ssB += red[i * 2 + 1]; }
    __syncthreads();                          // red dead before stages clobber

    // ---------------- Phase 1: T = A @ attT^T ----------------
    const int wm1 = (w & 1) * 64;             // 2 m-halves
    const int wn1 = (w >> 1) * 128;           // 4 n-chunks
    f32x4 acc1[4][8] = {};
    const int rA = tid >> 2, cA = tid & 3;    // stage decomposition

    GLDS(Ab + (size_t)(row0 + rA) * ND + cA * 8, sA0 + tid * 8);
    #pragma unroll
    for (int i = 0; i < 4; ++i) {
        int s = i * 512 + tid, r = s >> 2, c = s & 3;
        GLDS(attT + (size_t)r * ND + c * 8, sT0 + s * 8);
    }
    __syncthreads();

    for (int t = 0; t < 16; ++t) {
        if (t < 15) {                         // prefetch next k-step
            const int k0 = (t + 1) * 32;
            bf16* dA = (t & 1) ? sA0 : sA1;
            bf16* dT = (t & 1) ? sT0 : sT1;
            GLDS(Ab + (size_t)(row0 + rA) * ND + k0 + cA * 8, dA + tid * 8);
            #pragma unroll
            for (int i = 0; i < 4; ++i) {
                int s = i * 512 + tid, r = s >> 2, c = s & 3;
                GLDS(attT + (size_t)r * ND + k0 + c * 8, dT + s * 8);
            }
        } else {                              // prefetch phase-2's first tiles
            GLDS(Bb + (size_t)(row0 + rA) * ND + cA * 8, sB0 + tid * 8);
            GLDS(Ab + (size_t)(row0 + rA) * ND + cA * 8, sC0 + tid * 8);
        }
        const bf16* A_ = (t & 1) ? sA1 : sA0;
        const bf16* T_ = (t & 1) ? sT1 : sT0;
        bf16x8 af[4], bfm[8];
        #pragma unroll
        for (int t4 = 0; t4 < 4; ++t4)
            af[t4] = *(const bf16x8*)&A_[(wm1 + t4 * 16 + lm) * 32 + quad * 8];
        #pragma unroll
        for (int t8 = 0; t8 < 8; ++t8)
            bfm[t8] = *(const bf16x8*)&T_[(wn1 + t8 * 16 + lm) * 32 + quad * 8];
        #pragma unroll
        for (int im = 0; im < 4; ++im)
            #pragma unroll
            for (int jn = 0; jn < 8; ++jn)
                acc1[im][jn] = __builtin_amdgcn_mfma_f32_16x16x32_bf16(
                    af[im], bfm[jn], acc1[im][jn], 0, 0, 0);
        __syncthreads();
    }

    // Phase-1 epilogue: acc1 -> bf16 swizzled Tls (stage bufs dead).
    // Tls[ks][m][pos][e] with pos = kq ^ ((m>>2)&3), kq=(n>>3)&3, e=n&7.
    #pragma unroll
    for (int im = 0; im < 4; ++im)
    #pragma unroll
    for (int jn = 0; jn < 8; ++jn)
    #pragma unroll
    for (int p = 0; p < 4; ++p) {
        int m = wm1 + im * 16 + quad * 4 + p;   // C/D: col=lane&15, row=quad*4+reg
        int n = wn1 + jn * 16 + lm;
        int ks = n >> 5, kq = (n >> 3) & 3, e = n & 7;
        int pos = kq ^ ((m >> 2) & 3);
        Tls[ks * 4096 + m * 32 + pos * 8 + e] = (bf16)acc1[im][jn][p];
    }
    __syncthreads();

    // ------- Phase 2: S = T @ B^T  and  G = A @ diag(w) @ B^T -------
    const int wm2 = (w & 1) * 64;
    const int wn2 = (w >> 1) * 32;
    f32x4 acc2[4][2] = {}, accG[4][2] = {};

    for (int t = 0; t < 16; ++t) {
        if (t < 15) {
            bf16* dB = (t & 1) ? sB0 : sB1;
            bf16* dC = (t & 1) ? sC0 : sC1;
            GLDS(Bb + (size_t)(row0 + rA) * ND + (t + 1) * 32 + cA * 8, dB + tid * 8);
            GLDS(Ab + (size_t)(row0 + rA) * ND + (t + 1) * 32 + cA * 8, dC + tid * 8);
        }
        const bf16* B_ = (t & 1) ? sB1 : sB0;
        const bf16* C_ = (t & 1) ? sC1 : sC0;
        float4 w0 = *(const float4*)(w_pred + t * 32 + quad * 8);
        float4 w1 = *(const float4*)(w_pred + t * 32 + quad * 8 + 4);
        float wv[8] = {w0.x, w0.y, w0.z, w0.w, w1.x, w1.y, w1.z, w1.w};
        bf16x8 af[4], af2[4], bf2[2], bfw[2];
        #pragma unroll
        for (int t4 = 0; t4 < 4; ++t4) {
            int r = wm2 + t4 * 16 + lm;
            af[t4]  = *(const bf16x8*)&Tls[t * 4096 + r * 32 + ((quad ^ ((r >> 2) & 3))) * 8];
            af2[t4] = *(const bf16x8*)&C_[r * 32 + quad * 8];
        }
        #pragma unroll
        for (int t2 = 0; t2 < 2; ++t2) {
            bf2[t2] = *(const bf16x8*)&B_[(wn2 + t2 * 16 + lm) * 32 + quad * 8];
            #pragma unroll
            for (int j = 0; j < 8; ++j)
                bfw[t2][j] = (bf16)((float)bf2[t2][j] * wv[j]);
        }
        #pragma unroll
        for (int im = 0; im < 4; ++im)
            #pragma unroll
            for (int jn = 0; jn < 2; ++jn) {
                acc2[im][jn] = __builtin_amdgcn_mfma_f32_16x16x32_bf16(
                    af[im], bf2[jn], acc2[im][jn], 0, 0, 0);
                accG[im][jn] = __builtin_amdgcn_mfma_f32_16x16x32_bf16(
                    af2[im], bfw[jn], accG[im][jn], 0, 0, 0);
            }
        __syncthreads();
    }

    // ---- S epilogue: tanh + store + row/col sums (Tls dead -> smalls) ----
    const float sc = rsqrtf(ssA * ssB);
    float* __restrict__ Sb = Sout + (size_t)b * NL * NL;
    #pragma unroll
    for (int im = 0; im < 4; ++im)
    #pragma unroll
    for (int jn = 0; jn < 2; ++jn)
    #pragma unroll
    for (int p = 0; p < 4; ++p) {
        float v = tanhf(acc2[im][jn][p] * sc);
        acc2[im][jn][p] = v;
        int m = wm2 + im * 16 + quad * 4 + p;
        int n = wn2 + jn * 16 + lm;
        __builtin_nontemporal_store(v, &Sb[m * NL + n]);
    }
    #pragma unroll
    for (int im = 0; im < 4; ++im)
    #pragma unroll
    for (int p = 0; p < 4; ++p) {
        float r = acc2[im][0][p] + acc2[im][1][p];
        r += __shfl_xor(r, 1); r += __shfl_xor(r, 2);
        r += __shfl_xor(r, 4); r += __shfl_xor(r, 8);
        if (lm == 0) rowb[(w >> 1) * NL + wm2 + im * 16 + quad * 4 + p] = r;
    }
    #pragma unroll
    for (int jn = 0; jn < 2; ++jn) {
        float cv = 0.f;
        #pragma unroll
        for (int im = 0; im < 4; ++im)
            #pragma unroll
            for (int p = 0; p < 4; ++p) cv += acc2[im][jn][p];
        cv += __shfl_xor(cv, 16); cv += __shfl_xor(cv, 32);
        if (quad == 0) colb[(w & 1) * NL + wn2 + jn * 16 + lm] = cv;
    }
    __syncthreads();

    // ---- softmax over means (wave0: rows, wave1: cols) ----
    if (tid < 64) {
        float a  = (rowb[tid] + rowb[NL + tid] + rowb[2 * NL + tid] + rowb[3 * NL + tid]) * (1.f / NL);
        float c2 = (rowb[tid + 64] + rowb[NL + tid + 64] + rowb[2 * NL + tid + 64] + rowb[3 * NL + tid + 64]) * (1.f / NL);
        float mx = fmaxf(a, c2);
        for (int o = 32; o; o >>= 1) mx = fmaxf(mx, __shfl_xor(mx, o));
        float e0 = expf(a - mx), e1 = expf(c2 - mx);
        float s = e0 + e1;
        for (int o = 32; o; o >>= 1) s += __shfl_xor(s, o);
        float inv = 1.f / s;
        wrow[tid] = e0 * inv; wrow[tid + 64] = e1 * inv;
    } else if (tid < 128) {
        int q = tid - 64;
        float a  = (colb[q] + colb[NL + q]) * (1.f / NL);
        float c2 = (colb[q + 64] + colb[NL + q + 64]) * (1.f / NL);
        float mx = fmaxf(a, c2);
        for (int o = 32; o; o >>= 1) mx = fmaxf(mx, __shfl_xor(mx, o));
        float e0 = expf(a - mx), e1 = expf(c2 - mx);
        float s = e0 + e1;
        for (int o = 32; o; o >>= 1) s += __shfl_xor(s, o);
        float inv = 1.f / s;
        wcol[q] = e0 * inv; wcol[q + 64] = e1 * inv;
    }
    __syncthreads();

    // ---- logit = sc * wrow^T G wcol ----
    float wc0 = wcol[wn2 + lm], wc1 = wcol[wn2 + 16 + lm];
    float g = 0.f;
    #pragma unroll
    for (int im = 0; im < 4; ++im)
    #pragma unroll
    for (int p = 0; p < 4; ++p) {
        float wr = wrow[wm2 + im * 16 + quad * 4 + p];
        g += wr * (wc0 * accG[im][0][p] + wc1 * accG[im][1][p]);
    }
    for (int o = 32; o; o >>= 1) g += __shfl_xor(g, o);
    if (lane == 0) red2[w] = g;
    __syncthreads();
    if (tid == 0) {
        float tot = 0.f;
        #pragma unroll
        for (int i = 0; i < 8; ++i) tot += red2[i];
        logits[b] = tot * sc + b_pred[0];
    }
}

extern "C" void kernel_launch(void* const* d_in, const int* in_sizes, int n_in,
                              void* d_out, int out_size, void* d_ws, size_t ws_size,
                              hipStream_t stream) {
    const int*   t1c = (const int*)d_in[2];
    const int*   t2c = (const int*)d_in[3];
    const float* emb = (const float*)d_in[4];
    const float* att = (const float*)d_in[5];
    const float* wp  = (const float*)d_in[6];
    const float* bp  = (const float*)d_in[7];

    float* out    = (float*)d_out;
    float* logits = out;
    float* S      = out + NB;      // outputs: logits(512) then S(512*128*128)

    char* ws = (char*)d_ws;
    bf16*  Ab   = (bf16*)(ws);                              // 67,108,864 B
    bf16*  Bb   = (bf16*)(ws + 67108864);                   // 67,108,864 B
    bf16*  attT = (bf16*)(ws + 134217728);                  //    524,288 B

    k_attT<<<dim3(1024), 256, 0, stream>>>(att, attT);
    k_mega<<<dim3(NB), 512, 0, stream>>>(t1c, t2c, emb, attT, Ab, Bb,
                                         S, wp, bp, logits);
}